// Round 1
// baseline (83.303 us; speedup 1.0000x reference)
//
#include <hip/hip_runtime.h>

// GraphAttentionCriticNetwork fused kernel for MI355X (gfx950).
// B=256 graphs, one per block (256 blocks = 256 CUs, 1 block/CU due to ~138KB LDS).
// Math decomposition (see analysis): the O(N^3) reference collapses to
//   emb_a = Xa @ We^T (raw, for attention), ta = tanh(emb_a), diff = tanh(emb_p) - ta
//   w     = softmax_j(lrelu(src_i + dst_j))
//   G = W1a·ta /16, v = W1a·diff /16, us = W1s·states
//   u[i]  = us[i] + sum_k w[i,k]*G[k]
//   value[i,j] = W2 · lrelu(u[i] + w[i,j]*v[j])

#define NB 256

__global__ __launch_bounds__(256) void gacn_kernel(
    const float* __restrict__ states,    // [256,16,64]
    const float* __restrict__ policies,  // [256,16,8]
    const float* __restrict__ actions,   // [256,16,8]
    const float* __restrict__ W_emb,     // [128,72]
    const float* __restrict__ W_att,     // [256]
    const float* __restrict__ W1,        // [64,192]
    const float* __restrict__ W2,        // [64]
    float* __restrict__ out_value,       // [256,16,16]
    float* __restrict__ out_w)           // [256,16,16]
{
    // --- LDS ---
    // union region: sWe (phase A) is overwritten by GEMM partial slabs later.
    __shared__ __align__(16) float uni[13056];                 // 52224 B
    float (*sWe)[73]          = (float (*)[73])uni;            // [128][73]
    float (*slab)[3][16][68]  = (float (*)[3][16][68])uni;     // [4][3][16][68]
    __shared__ __align__(16) float sEraw[16][132];  // raw emb_a (for attention)
    __shared__ __align__(16) float sW1sw[64][192];  // W1, float4-granule XOR swizzled
    __shared__ __align__(16) float sTa[16][132];    // tanh(emb_a)
    __shared__ __align__(16) float sDf[16][132];    // tanh(emb_p) - tanh(emb_a)
    __shared__ float swgt[16][17];                  // softmax weights
    __shared__ __align__(16) float sG[16][68];      // (W1a . ta)/16
    __shared__ __align__(16) float sU[16][68];      // us, then u
    __shared__ __align__(16) float sV[16][68];      // (W1a . diff)/16
    __shared__ float ssrc[16];
    __shared__ float sdst[16];

    const int t = threadIdx.x;
    const int b = blockIdx.x;

    // ---- Stage weights into LDS (coalesced float4 reads) ----
    #pragma unroll
    for (int it = 0; it < 9; ++it) {                 // W_emb: 2304 float4
        const int idx = t + it * 256;
        const float4 v = ((const float4*)W_emb)[idx];
        const int r = idx / 18;
        const int c4 = idx - r * 18;
        float* dst = &sWe[r][c4 * 4];
        dst[0] = v.x; dst[1] = v.y; dst[2] = v.z; dst[3] = v.w;
    }
    #pragma unroll
    for (int it = 0; it < 12; ++it) {                // W1: 3072 float4, swizzled store
        const int idx = t + it * 256;
        const float4 v = ((const float4*)W1)[idx];
        const int h = idx / 48;
        const int g = idx - h * 48;
        const int gs = g ^ ((h >> 3) & 7);
        *(float4*)&sW1sw[h][gs * 4] = v;
    }
    __syncthreads();   // sync0

    // ---- Phase A: emb_a (raw + tanh), emb_p (tanh), diff ----
    // lanes -> d (128), wave-half -> k-half; x via wave-uniform scalar loads.
    {
        const int d = t & 127;
        const int khu = __builtin_amdgcn_readfirstlane(t >> 7);  // 0/1 wave-uniform
        float acc[8];
        #pragma unroll
        for (int kk = 0; kk < 8; ++kk) acc[kk] = 0.f;
        const float* stb = states + b * 1024 + khu * 512;
        #pragma unroll 8
        for (int c = 0; c < 64; ++c) {               // shared states part
            const float wv = sWe[d][c];
            #pragma unroll
            for (int kk = 0; kk < 8; ++kk)
                acc[kk] = fmaf(wv, stb[kk * 64 + c], acc[kk]);
        }
        float accA[8], accP[8];
        #pragma unroll
        for (int kk = 0; kk < 8; ++kk) { accA[kk] = acc[kk]; accP[kk] = acc[kk]; }
        const float* acb = actions  + b * 128 + khu * 64;
        const float* pob = policies + b * 128 + khu * 64;
        #pragma unroll
        for (int c = 0; c < 8; ++c) {                // action / policy tails
            const float wv = sWe[d][64 + c];
            #pragma unroll
            for (int kk = 0; kk < 8; ++kk) {
                accA[kk] = fmaf(wv, acb[kk * 8 + c], accA[kk]);
                accP[kk] = fmaf(wv, pob[kk * 8 + c], accP[kk]);
            }
        }
        #pragma unroll
        for (int kk = 0; kk < 8; ++kk) {
            const int k = khu * 8 + kk;
            sEraw[k][d] = accA[kk];
            const float ta = tanhf(accA[kk]);
            const float tp = tanhf(accP[kk]);
            sTa[k][d] = ta;
            sDf[k][d] = tp - ta;
        }
    }
    __syncthreads();   // sync1

    // ---- Phase B: src/dst attention scores (dot(emb_raw, W_att halves)) ----
    {
        const int k = t >> 4;
        const int w = (t >> 3) & 1;
        const int s = t & 7;
        float part = 0.f;
        #pragma unroll
        for (int c4 = 0; c4 < 4; ++c4) {
            const float4 e = *(const float4*)&sEraw[k][s * 16 + c4 * 4];
            const float4 a = *(const float4*)&W_att[w * 128 + s * 16 + c4 * 4];
            part += e.x * a.x + e.y * a.y + e.z * a.z + e.w * a.w;
        }
        part += __shfl_xor(part, 1);
        part += __shfl_xor(part, 2);
        part += __shfl_xor(part, 4);
        if (s == 0) { if (w) sdst[k] = part; else ssrc[k] = part; }
    }
    __syncthreads();   // sync2

    // ---- Phase C: softmax over j (16-lane groups), write ret_weight ----
    {
        const int i = t >> 4;
        const int j = t & 15;
        float sc = ssrc[i] + sdst[j];
        sc = fmaxf(sc, 0.01f * sc);                  // leaky_relu slope 0.01
        float mx = sc;
        mx = fmaxf(mx, __shfl_xor(mx, 1));
        mx = fmaxf(mx, __shfl_xor(mx, 2));
        mx = fmaxf(mx, __shfl_xor(mx, 4));
        mx = fmaxf(mx, __shfl_xor(mx, 8));
        const float e = expf(sc - mx);
        float sm = e;
        sm += __shfl_xor(sm, 1);
        sm += __shfl_xor(sm, 2);
        sm += __shfl_xor(sm, 4);
        sm += __shfl_xor(sm, 8);
        const float w = e / sm;
        swgt[i][j] = w;
        out_w[b * 256 + t] = w;
    }

    // ---- GEMM: G~ = W1a.ta, V~ = W1a.diff, Us = W1s.states (c-split x 4 waves) ----
    {
        const int wid = t >> 6;
        const int rl = t & 7;
        const int hs = (t >> 3) & 7;
        #pragma unroll
        for (int m = 0; m < 2; ++m) {
            const float (*X)[132] = (m == 0) ? sTa : sDf;
            float a0[8], a1[8];
            #pragma unroll
            for (int hh = 0; hh < 8; ++hh) { a0[hh] = 0.f; a1[hh] = 0.f; }
            #pragma unroll
            for (int ch = 0; ch < 8; ++ch) {
                const int c0 = wid * 32 + ch * 4;
                const float4 x0 = *(const float4*)&X[rl][c0];
                const float4 x1 = *(const float4*)&X[8 + rl][c0];
                const int gs = ((16 + (c0 >> 2)) ^ hs) * 4;   // W1 col 64+c0
                #pragma unroll
                for (int hh = 0; hh < 8; ++hh) {
                    const float4 wf = *(const float4*)&sW1sw[hs * 8 + hh][gs];
                    a0[hh] = fmaf(wf.x, x0.x, a0[hh]);
                    a0[hh] = fmaf(wf.y, x0.y, a0[hh]);
                    a0[hh] = fmaf(wf.z, x0.z, a0[hh]);
                    a0[hh] = fmaf(wf.w, x0.w, a0[hh]);
                    a1[hh] = fmaf(wf.x, x1.x, a1[hh]);
                    a1[hh] = fmaf(wf.y, x1.y, a1[hh]);
                    a1[hh] = fmaf(wf.z, x1.z, a1[hh]);
                    a1[hh] = fmaf(wf.w, x1.w, a1[hh]);
                }
            }
            #pragma unroll
            for (int hh = 0; hh < 8; ++hh) {
                slab[wid][m][rl][hs * 8 + hh] = a0[hh];
                slab[wid][m][8 + rl][hs * 8 + hh] = a1[hh];
            }
        }
        {   // states part (W1 cols 0..63), states read from global (L1-hot)
            const float* stb = states + b * 1024;
            float a0[8], a1[8];
            #pragma unroll
            for (int hh = 0; hh < 8; ++hh) { a0[hh] = 0.f; a1[hh] = 0.f; }
            #pragma unroll
            for (int ch = 0; ch < 4; ++ch) {
                const int c0 = wid * 16 + ch * 4;
                const float4 x0 = *(const float4*)&stb[rl * 64 + c0];
                const float4 x1 = *(const float4*)&stb[(8 + rl) * 64 + c0];
                const int gs = ((c0 >> 2) ^ hs) * 4;
                #pragma unroll
                for (int hh = 0; hh < 8; ++hh) {
                    const float4 wf = *(const float4*)&sW1sw[hs * 8 + hh][gs];
                    a0[hh] = fmaf(wf.x, x0.x, a0[hh]);
                    a0[hh] = fmaf(wf.y, x0.y, a0[hh]);
                    a0[hh] = fmaf(wf.z, x0.z, a0[hh]);
                    a0[hh] = fmaf(wf.w, x0.w, a0[hh]);
                    a1[hh] = fmaf(wf.x, x1.x, a1[hh]);
                    a1[hh] = fmaf(wf.y, x1.y, a1[hh]);
                    a1[hh] = fmaf(wf.z, x1.z, a1[hh]);
                    a1[hh] = fmaf(wf.w, x1.w, a1[hh]);
                }
            }
            #pragma unroll
            for (int hh = 0; hh < 8; ++hh) {
                slab[wid][2][rl][hs * 8 + hh] = a0[hh];
                slab[wid][2][8 + rl][hs * 8 + hh] = a1[hh];
            }
        }
    }
    __syncthreads();   // sync3

    // ---- Reduce 4 wave-partials -> sG (/16), sV (/16), sU (raw us) ----
    #pragma unroll
    for (int q = 0; q < 12; ++q) {
        const int flat = t + q * 256;                // 0..3071
        const int m = flat >> 10;
        const int r = (flat >> 6) & 15;
        const int h = flat & 63;
        const float s = slab[0][m][r][h] + slab[1][m][r][h]
                      + slab[2][m][r][h] + slab[3][m][r][h];
        if (m == 0)      sG[r][h] = s * 0.0625f;
        else if (m == 1) sV[r][h] = s * 0.0625f;
        else             sU[r][h] = s;
    }
    __syncthreads();   // sync4

    // ---- Phase E: u[i][h] = us[i][h] + sum_k w[i,k] * G[k][h] ----
    {
        const int h = t & 63;
        const int ig = t >> 6;                       // wave-uniform
        float au[4];
        #pragma unroll
        for (int ii = 0; ii < 4; ++ii) au[ii] = 0.f;
        #pragma unroll
        for (int k = 0; k < 16; ++k) {
            const float g = sG[k][h];
            #pragma unroll
            for (int ii = 0; ii < 4; ++ii)
                au[ii] = fmaf(swgt[ig * 4 + ii][k], g, au[ii]);
        }
        #pragma unroll
        for (int ii = 0; ii < 4; ++ii) {
            const int i = ig * 4 + ii;
            sU[i][h] += au[ii];
        }
    }
    __syncthreads();   // sync5

    // ---- Phase G: value[i,j] = W2 . lrelu(u[i] + w[i,j]*v[j]) ----
    {
        const int i = t >> 4;
        const int j = t & 15;
        const float wij = swgt[i][j];
        float acc = 0.f;
        #pragma unroll
        for (int h4 = 0; h4 < 16; ++h4) {
            const float4 uu = *(const float4*)&sU[i][h4 * 4];
            const float4 vv = *(const float4*)&sV[j][h4 * 4];
            const float4 w2 = *(const float4*)&W2[h4 * 4];   // uniform -> s_load
            float x;
            x = fmaf(wij, vv.x, uu.x); x = fmaxf(x, 0.01f * x); acc = fmaf(w2.x, x, acc);
            x = fmaf(wij, vv.y, uu.y); x = fmaxf(x, 0.01f * x); acc = fmaf(w2.y, x, acc);
            x = fmaf(wij, vv.z, uu.z); x = fmaxf(x, 0.01f * x); acc = fmaf(w2.z, x, acc);
            x = fmaf(wij, vv.w, uu.w); x = fmaxf(x, 0.01f * x); acc = fmaf(w2.w, x, acc);
        }
        out_value[b * 256 + t] = acc;
    }
}

extern "C" void kernel_launch(void* const* d_in, const int* in_sizes, int n_in,
                              void* d_out, int out_size, void* d_ws, size_t ws_size,
                              hipStream_t stream) {
    const float* states   = (const float*)d_in[0];
    const float* policies = (const float*)d_in[1];
    const float* actions  = (const float*)d_in[2];
    const float* W_emb    = (const float*)d_in[3];
    const float* W_att    = (const float*)d_in[4];
    const float* W1       = (const float*)d_in[5];
    const float* W2       = (const float*)d_in[6];
    float* out = (float*)d_out;
    gacn_kernel<<<NB, 256, 0, stream>>>(states, policies, actions,
                                        W_emb, W_att, W1, W2,
                                        out, out + 256 * 16 * 16);
}